// Round 3
// baseline (775.356 us; speedup 1.0000x reference)
//
#include <hip/hip_runtime.h>
#include <hip/hip_bf16.h>
#include <stdint.h>

typedef unsigned short u16t;
typedef __attribute__((ext_vector_type(8))) short short8;
typedef __attribute__((ext_vector_type(4))) float floatx4;
typedef __attribute__((ext_vector_type(16))) float floatx16;

__device__ __forceinline__ float bf2f(u16t u) {
  union { unsigned int i; float f; } v; v.i = ((unsigned int)u) << 16; return v.f;
}
__device__ __forceinline__ u16t f2bf(float f) {
  union { float f; unsigned int i; } v; v.f = f;
  unsigned int x = v.i;
  return (u16t)((x + 0x7fffu + ((x >> 16) & 1u)) >> 16);  // RNE, no NaNs here
}
__device__ __forceinline__ void async_copy16(const void* g, void* l) {
  __builtin_amdgcn_global_load_lds(
      (const __attribute__((address_space(1))) void*)g,
      (__attribute__((address_space(3))) void*)l, 16, 0, 0);
}

// ---------------- prep: x fp32 -> dec[:, :256] bf16  +  xT[B][D][T] bf16 ----
__global__ __launch_bounds__(256) void prep_x(const float* __restrict__ x,
                                              u16t* __restrict__ dec,
                                              u16t* __restrict__ xT) {
  __shared__ u16t tile[64 * 65];
  const int tid = threadIdx.x;
  const int b = blockIdx.z, t0 = blockIdx.y * 64, d0 = blockIdx.x * 64;
  const int r = tid >> 2, cb = (tid & 3) << 4;
  const float* gx = x + ((size_t)(b * 2048 + t0 + r) * 256 + d0 + cb);
  union { uint4 v[2]; u16t u[16]; } pk;
#pragma unroll
  for (int j = 0; j < 16; j += 4) {
    float4 f = *(const float4*)(gx + j);
    pk.u[j + 0] = f2bf(f.x); pk.u[j + 1] = f2bf(f.y);
    pk.u[j + 2] = f2bf(f.z); pk.u[j + 3] = f2bf(f.w);
  }
  u16t* gd = dec + ((size_t)(b * 2048 + t0 + r) * 512 + d0 + cb);
  *(uint4*)(gd) = pk.v[0];
  *(uint4*)(gd + 8) = pk.v[1];
#pragma unroll
  for (int j = 0; j < 16; ++j) tile[r * 65 + cb + j] = pk.u[j];
  __syncthreads();
  union { uint4 v[2]; u16t u[16]; } pk2;
#pragma unroll
  for (int j = 0; j < 16; ++j) pk2.u[j] = tile[(cb + j) * 65 + r];
  u16t* gt = xT + ((size_t)(b * 256 + d0 + r) * 2048 + t0 + cb);
  *(uint4*)(gt) = pk2.v[0];
  *(uint4*)(gt + 8) = pk2.v[1];
}

// ---------------- prep: W [K][N] fp32 -> WT [N][K] bf16 ---------------------
__global__ __launch_bounds__(256) void prep_w(const float* __restrict__ W,
                                              u16t* __restrict__ WT,
                                              int K, int N) {
  __shared__ u16t tile[64 * 65];
  const int tid = threadIdx.x;
  const int n0 = blockIdx.x * 64, k0 = blockIdx.y * 64;
  const int r = tid >> 2, cb = (tid & 3) << 4;
  const float* gw = W + ((size_t)(k0 + r) * N + n0 + cb);
#pragma unroll
  for (int j = 0; j < 16; j += 4) {
    float4 f = *(const float4*)(gw + j);
    tile[r * 65 + cb + j + 0] = f2bf(f.x);
    tile[r * 65 + cb + j + 1] = f2bf(f.y);
    tile[r * 65 + cb + j + 2] = f2bf(f.z);
    tile[r * 65 + cb + j + 3] = f2bf(f.w);
  }
  __syncthreads();
  union { uint4 v[2]; u16t u[16]; } pk;
#pragma unroll
  for (int j = 0; j < 16; ++j) pk.u[j] = tile[(cb + j) * 65 + r];
  u16t* gt = WT + ((size_t)(n0 + r) * K + k0 + cb);
  *(uint4*)(gt) = pk.v[0];
  *(uint4*)(gt + 8) = pk.v[1];
}

// ---------------- flash attention v4 --------------------------------------
// 128 q-rows per block, 32-key tiles, 4 q-waves (wq=0..3, 32 q each).
// Fixed-max softmax (exp2 domain, offset 16): no running max, no rescale,
// no cross-wave reductions. S^T via mfma(K, Q^T); P converted C-layout ->
// B-operand layout with 4 shfl_xor(32); O^T accumulated over all 256 d per
// wave (8 tiles). Double-buffered staging, 1 barrier per k-tile.
__global__ __launch_bounds__(256, 2) void attn(u16t* __restrict__ dec,
                                               const u16t* __restrict__ xT) {
  __shared__ char smem[65536];  // [2] x (Kt 16KB | Vt 16KB)
  const int tid = threadIdx.x;
  const int wq = tid >> 6, lane = tid & 63;
  const int l31 = lane & 31, hl = lane >> 5;
  const int bi = blockIdx.x;
  const int hi = bi >> 8, kk = bi & 255;
  const int qt = hi ? (kk & 15) : 15 - (kk & 15);   // heavy/light pairing
  const int b = ((kk >> 4) & 15) | (hi << 4);
  const int q0 = qt << 7;
  const int qg = q0 + wq * 32 + l31;  // this lane's q row (within batch)

  // Q B-frags (scaled by log2e/16): qf[s] element j <-> d = 16s + 8hl + j
  short8 qf[16];
  {
    const u16t* qp = dec + ((size_t)(b * 2048 + qg) * 512) + hl * 8;
    const float qs = 1.44269504f / 16.0f;
#pragma unroll
    for (int s = 0; s < 16; ++s) {
      union { uint4 v; u16t u[8]; } in;
      union { short8 s8; u16t u[8]; } ot;
      in.v = *(const uint4*)(qp + s * 16);
#pragma unroll
      for (int j = 0; j < 8; ++j) ot.u[j] = f2bf(bf2f(in.u[j]) * qs);
      qf[s] = ot.s8;
    }
  }

  floatx16 o[8];  // O^T: d = dt*32 + rowpat, q = l31 (col)
#pragma unroll
  for (int t = 0; t < 8; ++t)
#pragma unroll
    for (int r = 0; r < 16; ++r) o[t][r] = 0.f;
  float l_r = 0.f;

  const int nk = 4 * qt + 4;

  auto stage = [&](int kt, int bsel) {
    char* Kb = smem + bsel * 32768;
    char* Vb = Kb + 16384;
    const int k0 = kt << 5;
#pragma unroll
    for (int ii = 0; ii < 4; ++ii) {  // K: 32 keys x 32 chunks(8d)
      int c = ii * 256 + tid;
      int key = c >> 5, cs = (c & 31) ^ (key & 7);
      async_copy16(dec + ((size_t)(b * 2048 + k0 + key) * 512) + cs * 8,
                   Kb + c * 16);
    }
#pragma unroll
    for (int ii = 0; ii < 4; ++ii) {  // V^T: 256 d x 4 chunks(8keys)
      int c = ii * 256 + tid;
      int d = c >> 2, cs = (c & 3) ^ ((d >> 1) & 3);
      async_copy16(xT + ((size_t)(b * 256 + d) * 2048) + k0 + cs * 8,
                   Vb + c * 16);
    }
  };

  stage(0, 0);
  for (int kt = 0; kt < nk; ++kt) {
    __syncthreads();  // buf[kt&1] staged (drain) + prev reads complete
    if (kt + 1 < nk) stage(kt + 1, (kt + 1) & 1);
    const char* Kb = smem + (kt & 1) * 32768;
    const char* Vb = Kb + 16384;
    const int k0 = kt << 5;
    if (k0 <= q0 + wq * 32 + 30) {  // wave-uniform: this tile has unmasked keys
      // stage 1: S^T (32 keys x 32 q) = K Q^T
      floatx16 st;
#pragma unroll
      for (int r = 0; r < 16; ++r) st[r] = 0.f;
#pragma unroll
      for (int s = 0; s < 16; ++s) {
        int slot = (2 * s + hl) ^ (l31 & 7);
        short8 kf = *(const short8*)(Kb + (l31 * 32 + slot) * 16);
        st = __builtin_amdgcn_mfma_f32_32x32x16_bf16(kf, qf[s], st, 0, 0, 0);
      }
      if (k0 + 31 >= q0 + wq * 32) {  // strict causal mask on boundary tile
#pragma unroll
        for (int r = 0; r < 16; ++r) {
          int keyg = k0 + (r & 3) + 8 * (r >> 2) + 4 * hl;
          if (keyg >= qg) st[r] = -1e30f;
        }
      }
      // fixed-max softmax terms: p = exp2(st - 16)
      float ps = 0.f;
      unsigned int pk[8];
#pragma unroll
      for (int ii = 0; ii < 8; ++ii) {
        float p0 = exp2f(st[2 * ii] - 16.f);
        float p1 = exp2f(st[2 * ii + 1] - 16.f);
        ps += p0 + p1;
        union { __hip_bfloat162 h2; unsigned int u; } cv;
        cv.h2 = __float22bfloat162_rn(float2{p0, p1});
        pk[ii] = cv.u;
      }
      ps += __shfl_xor(ps, 32, 64);
      l_r += ps;
      // stage 2: O^T += V^T P^T ; P B-frags built via half-wave exchange
#pragma unroll
      for (int ks = 0; ks < 2; ++ks) {
        const int ka = 2 * ks + hl;       // keep: own group
        const int sa = 2 * ks + 1 - hl;   // send: partner-needed group
        unsigned int rv0 = __shfl_xor((int)pk[2 * sa], 32, 64);
        unsigned int rv1 = __shfl_xor((int)pk[2 * sa + 1], 32, 64);
        union { unsigned int u[4]; short8 s8; } fr;
        if (hl == 0) {
          fr.u[0] = pk[2 * ka]; fr.u[1] = pk[2 * ka + 1];
          fr.u[2] = rv0;        fr.u[3] = rv1;
        } else {
          fr.u[0] = rv0;        fr.u[1] = rv1;
          fr.u[2] = pk[2 * ka]; fr.u[3] = pk[2 * ka + 1];
        }
#pragma unroll
        for (int dt = 0; dt < 8; ++dt) {
          int d = dt * 32 + l31;
          int slot = (2 * ks + hl) ^ ((d >> 1) & 3);
          short8 vf = *(const short8*)(Vb + (d * 4 + slot) * 16);
          o[dt] = __builtin_amdgcn_mfma_f32_32x32x16_bf16(vf, fr.s8, o[dt], 0, 0, 0);
        }
      }
    }
  }
  // epilogue: ctx = O/l (q=0 -> l=0 -> writes 0, matching reference)
  const float linv = (l_r > 0.f) ? 1.f / l_r : 0.f;
  u16t* outp = dec + ((size_t)(b * 2048 + qg) * 512) + 256;
#pragma unroll
  for (int dt = 0; dt < 8; ++dt)
#pragma unroll
    for (int a = 0; a < 4; ++a) {
      union { uint2 v; u16t u[4]; } w;
#pragma unroll
      for (int e = 0; e < 4; ++e) w.u[e] = f2bf(o[dt][4 * a + e] * linv);
      *(uint2*)(outp + dt * 32 + 8 * a + 4 * hl) = w.v;
    }
}

// ---------------- GEMM v3: weights streamed from global (L2-resident) ------
// C = A[M,K] * BT[N,K]^T + bias. Block 128m x 256n, wave 64m x 128n.
// LDS stages A only (double-buffered); BT frags loaded per-lane from global.
// MODE 0: relu -> bf16 [M,N]. MODE 1: fp32 split-write to d_out.
template <int MODE>
__global__ __launch_bounds__(256, 2) void gemm(const u16t* __restrict__ A,
                                               const u16t* __restrict__ BT,
                                               const float* __restrict__ bias,
                                               void* __restrict__ outp,
                                               int N, int K) {
  __shared__ char smem[32768];  // A dbuf: 2 x 16KB (128 rows x 64k)
  const int tid = threadIdx.x;
  const int lane = tid & 63, wid = tid >> 6, quad = lane >> 4, l15 = lane & 15;
  const int wm = wid >> 1, wn = wid & 1;
  const int m0 = blockIdx.y << 7, n0 = blockIdx.x << 8;
  floatx4 acc[4][8];
#pragma unroll
  for (int mi = 0; mi < 4; ++mi)
#pragma unroll
    for (int jn = 0; jn < 8; ++jn) acc[mi][jn] = (floatx4){0.f, 0.f, 0.f, 0.f};
  const int kit = K >> 6;
  auto stageA = [&](int kkk, int bsel) {
    const int k0 = kkk << 6;
    char* buf = smem + bsel * 16384;
#pragma unroll
    for (int ii = 0; ii < 4; ++ii) {
      int c = ii * 256 + tid;
      int r = c >> 3, q = (c & 7) ^ (r & 7);
      async_copy16(A + ((size_t)(m0 + r) * K) + k0 + q * 8, buf + c * 16);
    }
  };
  stageA(0, 0);
  for (int kk = 0; kk < kit; ++kk) {
    __syncthreads();
    if (kk + 1 < kit) stageA(kk + 1, (kk + 1) & 1);
    const char* buf = smem + (kk & 1) * 16384;
    const int k0 = kk << 6;
    short8 bfr[2][8];
#pragma unroll
    for (int s2 = 0; s2 < 2; ++s2)
#pragma unroll
      for (int jn = 0; jn < 8; ++jn) {
        int n = n0 + wn * 128 + jn * 16 + l15;
        bfr[s2][jn] =
            *(const short8*)(BT + (size_t)n * K + k0 + (s2 * 4 + quad) * 8);
      }
#pragma unroll
    for (int s2 = 0; s2 < 2; ++s2) {
      short8 af[4];
#pragma unroll
      for (int mi = 0; mi < 4; ++mi) {
        int m = wm * 64 + mi * 16 + l15;
        af[mi] =
            *(const short8*)(buf + ((m * 8 + ((s2 * 4 + quad) ^ (m & 7))) * 16));
      }
#pragma unroll
      for (int mi = 0; mi < 4; ++mi)
#pragma unroll
        for (int jn = 0; jn < 8; ++jn)  // swapped operands -> C^T fragments
          acc[mi][jn] = __builtin_amdgcn_mfma_f32_16x16x32_bf16(
              bfr[s2][jn], af[mi], acc[mi][jn], 0, 0, 0);
    }
  }
  // epilogue: lane holds C[row=m0+wm*64+mi*16+l15][cols base+quad*4+0..3]
#pragma unroll
  for (int jn = 0; jn < 8; ++jn) {
    const float4 bv = *(const float4*)(bias + n0 + wn * 128 + jn * 16 + quad * 4);
#pragma unroll
    for (int mi = 0; mi < 4; ++mi) {
      const int row = m0 + wm * 64 + mi * 16 + l15;
      const int ncol = wn * 128 + jn * 16 + quad * 4;
      float v0 = acc[mi][jn][0] + bv.x;
      float v1 = acc[mi][jn][1] + bv.y;
      float v2 = acc[mi][jn][2] + bv.z;
      float v3 = acc[mi][jn][3] + bv.w;
      if (MODE == 0) {
        union { uint2 v; u16t u[4]; } w;
        w.u[0] = f2bf(fmaxf(v0, 0.f)); w.u[1] = f2bf(fmaxf(v1, 0.f));
        w.u[2] = f2bf(fmaxf(v2, 0.f)); w.u[3] = f2bf(fmaxf(v3, 0.f));
        *(uint2*)((u16t*)outp + (size_t)row * N + n0 + ncol) = w.v;
      } else {
        float* po = (float*)outp + ((size_t)(n0 >> 8)) * 16777216ull;
        *(float4*)(po + (size_t)row * 256 + ncol) = (float4){v0, v1, v2, v3};
      }
    }
  }
}

// ---------------- launch ----------------------------------------------------
extern "C" void kernel_launch(void* const* d_in, const int* in_sizes, int n_in,
                              void* d_out, int out_size, void* d_ws, size_t ws_size,
                              hipStream_t stream) {
  const float* x  = (const float*)d_in[0];
  const float* W1 = (const float*)d_in[1];
  const float* b1 = (const float*)d_in[2];
  const float* W2 = (const float*)d_in[3];
  const float* b2 = (const float*)d_in[4];
  char* ws = (char*)d_ws;
  u16t* dec = (u16t*)ws;                                     // [65536][512] bf16
  u16t* h   = (u16t*)(ws + 67108864ull);                     // [65536][1024] bf16
  u16t* xT  = (u16t*)(ws + 67108864ull);                     // [32][256][2048] (dead before gemm0 writes h)
  u16t* W1T = (u16t*)(ws + 67108864ull + 134217728ull);      // [1024][512]
  u16t* W2T = (u16t*)(ws + 67108864ull + 134217728ull + 1048576ull);  // [512][1024]

  prep_x<<<dim3(4, 32, 32), 256, 0, stream>>>(x, dec, xT);
  prep_w<<<dim3(16, 8), 256, 0, stream>>>(W1, W1T, 512, 1024);
  prep_w<<<dim3(8, 16), 256, 0, stream>>>(W2, W2T, 1024, 512);
  attn<<<512, 256, 0, stream>>>(dec, xT);
  gemm<0><<<dim3(4, 512), 256, 0, stream>>>(dec, W1T, b1, (void*)h, 1024, 512);
  gemm<1><<<dim3(2, 512), 256, 0, stream>>>(h, W2T, b2, d_out, 512, 1024);
}